// Round 1
// baseline (17520.064 us; speedup 1.0000x reference)
//
#include <hip/hip_runtime.h>
#include <math.h>

#define NSTATES 1024
#define TT      4096
#define DD      20

#define FW_BLOCKS  64
#define FW_THREADS 256
#define JPB  16      // j per block   (FW_BLOCKS * JPB = NSTATES)
#define NSEG 16      // k segments    (JPB * NSEG = FW_THREADS)
#define KSEG 64      // k per segment (NSEG * KSEG = NSTATES)

// workspace layout (bytes)
#define OFF_LAT   ((size_t)0)                       // 4 MB  logA transposed: lat[j*N+k] = log(trans[k][j])
#define OFF_E     ((size_t)4 << 20)                 // 16 MB emissions E[t*N+n]
#define OFF_COL0  ((size_t)20 << 20)                // 4 KB
#define OFF_COL1  (((size_t)20 << 20) + 4096)       // 4 KB
#define OFF_FLAGS (((size_t)20 << 20) + 8192)       // 4 KB (64 flags, 64B stride)
#define OFF_PTR   ((size_t)21 << 20)                // 8 MB  u16 backpointers, rows 1..T-1

__global__ void k_logtrans(const float* __restrict__ tr, float* __restrict__ lat) {
    int id = blockIdx.x * 256 + threadIdx.x;        // 1M threads
    int k = id >> 10, j = id & 1023;
    lat[(size_t)j * NSTATES + k] = logf(tr[id]);    // coalesced read, strided write (one-time)
}

__global__ void k_emis(const float* __restrict__ ev, const float* __restrict__ epar,
                       const float* __restrict__ prior, float* __restrict__ E,
                       float* __restrict__ col0) {
    int n = blockIdx.x * 256 + threadIdx.x;         // 4 x 256 = 1024
    int t = blockIdx.y;                             // 0..4095
    const float* ep = epar + (size_t)n * (2 * DD);
    const float* x  = ev + (size_t)t * DD;
    float acc = 0.0f;
    #pragma unroll
    for (int d = 0; d < DD; ++d) {
        float m = ep[2 * d];
        float s = ep[2 * d + 1];
        // faithful to reference: p = (2*pi*s)^(-0.5) * exp(-(x-m)^2/(2*s^2)); logp = log(p)
        float tp   = 6.2831853071795864769f * s;
        float coef = 1.0f / sqrtf(tp);
        float df   = x[d] - m;
        float num  = df * df;
        float den  = 2.0f * (s * s);
        float p    = coef * expf(-num / den);
        acc += logf(p);                             // -inf propagates, matching nan_to_num(posinf/neginf kept)
    }
    E[(size_t)t * NSTATES + n] = acc;
    if (t == 0) col0[n] = logf(prior[n]) + acc;     // col0 = log(prior) + logp0
}

__global__ __launch_bounds__(FW_THREADS, 1) void k_forward(
    const float* __restrict__ lat, const float* __restrict__ E,
    float* __restrict__ col0, float* __restrict__ col1,
    unsigned short* __restrict__ bptr, int* __restrict__ flags)
{
    __shared__ float prevs[NSTATES];
    __shared__ float smax[NSEG][JPB];
    __shared__ unsigned short sidx[NSEG][JPB];
    const int tid  = threadIdx.x;
    const int jj   = tid & (JPB - 1);
    const int seg  = tid >> 4;                       // 0..15
    const int j    = blockIdx.x * JPB + jj;
    const int kbase = seg * KSEG;
    const float* lrow = lat + (size_t)j * NSTATES + kbase;

    for (int t = 1; t < TT; ++t) {
        const float* prev = (t & 1) ? col0 : col1;
        float* next       = (t & 1) ? col1 : col0;

        // barrier: wait until every block has finished step t-1 (monotonic flags)
        if (tid < FW_BLOCKS) {
            while (__hip_atomic_load(&flags[tid * 16], __ATOMIC_ACQUIRE,
                                     __HIP_MEMORY_SCOPE_AGENT) < t - 1) { }
        }
        __syncthreads();

        // stage prev column to LDS (1024 floats, float4 per thread)
        ((float4*)prevs)[tid] = ((const float4*)prev)[tid];
        __syncthreads();

        // per-lane scan of its k-segment for its j: first-max (strict >, ascending k)
        float best = -__builtin_inff();
        int bidx = kbase;
        #pragma unroll
        for (int u = 0; u < KSEG / 4; ++u) {
            float4 w = *(const float4*)(lrow + u * 4);
            float4 p = *(const float4*)(prevs + kbase + u * 4);
            int k0 = kbase + u * 4;
            float v0 = p.x + w.x;
            float v1 = p.y + w.y;
            float v2 = p.z + w.z;
            float v3 = p.w + w.w;
            if (v0 > best) { best = v0; bidx = k0;     }
            if (v1 > best) { best = v1; bidx = k0 + 1; }
            if (v2 > best) { best = v2; bidx = k0 + 2; }
            if (v3 > best) { best = v3; bidx = k0 + 3; }
        }
        smax[seg][jj] = best;
        sidx[seg][jj] = (unsigned short)bidx;
        __syncthreads();

        // combine 16 segment partials per j, ascending seg => global first-max
        if (tid < JPB) {
            float m = smax[0][tid];
            int  mi = sidx[0][tid];
            #pragma unroll
            for (int s2 = 1; s2 < NSEG; ++s2) {
                float v = smax[s2][tid];
                if (v > m) { m = v; mi = sidx[s2][tid]; }
            }
            int jw = blockIdx.x * JPB + tid;
            // reference quirk: j==0 value is forced from state 0 (ptr still stores the true argmax)
            float val = (jw == 0) ? (prevs[0] + lat[0]) : m;
            next[jw] = val + E[(size_t)t * NSTATES + jw];
            bptr[(size_t)t * NSTATES + jw] = (unsigned short)mi;
        }
        __syncthreads();
        // release: all col/ptr stores above were issued by wave 0; tid 0 is in wave 0,
        // so the agent-scope release (s_waitcnt vmcnt(0) + L2 writeback) covers them.
        if (tid == 0) {
            __hip_atomic_store(&flags[blockIdx.x * 16], t, __ATOMIC_RELEASE,
                               __HIP_MEMORY_SCOPE_AGENT);
        }
    }
}

#define BTC 24  // ptr rows per LDS chunk (48 KB)
__global__ void k_backtrace(const float* __restrict__ lastcol,
                            const unsigned short* __restrict__ bptr,
                            int* __restrict__ seq)
{
    __shared__ unsigned short ring[BTC][NSTATES];
    __shared__ int s_front;
    const int lane = threadIdx.x;   // 64 threads = 1 wave

    // last = first-max argmax over final column
    float best = -__builtin_inff();
    int bi = 0;
    for (int n2 = lane; n2 < NSTATES; n2 += 64) {
        float v = lastcol[n2];
        if (v > best) { best = v; bi = n2; }
    }
    #pragma unroll
    for (int off = 32; off > 0; off >>= 1) {
        float ov = __shfl_xor(best, off);
        int   oi = __shfl_xor(bi, off);
        if (ov > best || (ov == best && oi < bi)) { best = ov; bi = oi; }
    }
    if (lane == 0) { seq[TT] = bi; seq[TT - 1] = bi; s_front = bi; }
    __syncthreads();

    // chase rows r = T-1 .. 1 (seq[r-1] = ptr[r][front]) in descending LDS chunks
    for (int rhi = TT - 1; rhi >= 1; rhi -= BTC) {
        int rlo = rhi - (BTC - 1);
        if (rlo < 1) rlo = 1;
        for (int rr = rlo; rr <= rhi; ++rr) {
            const uint4* src = (const uint4*)(bptr + (size_t)rr * NSTATES);
            uint4* dst = (uint4*)(&ring[rr - rlo][0]);
            dst[lane]      = src[lane];
            dst[lane + 64] = src[lane + 64];
        }
        __syncthreads();
        if (lane == 0) {
            int front = s_front;
            for (int r = rhi; r >= rlo; --r) {
                front = (int)ring[r - rlo][front];
                seq[r - 1] = front;
            }
            s_front = front;
        }
        __syncthreads();
    }
}

extern "C" void kernel_launch(void* const* d_in, const int* in_sizes, int n_in,
                              void* d_out, int out_size, void* d_ws, size_t ws_size,
                              hipStream_t stream) {
    const float* ev    = (const float*)d_in[0];   // [T, D]
    const float* prior = (const float*)d_in[1];   // [N]
    const float* tr    = (const float*)d_in[2];   // [N, N]
    const float* epar  = (const float*)d_in[3];   // [N, D, 2]
    int* seq = (int*)d_out;                       // [T+1]
    char* ws = (char*)d_ws;
    float* lat  = (float*)(ws + OFF_LAT);
    float* E    = (float*)(ws + OFF_E);
    float* col0 = (float*)(ws + OFF_COL0);
    float* col1 = (float*)(ws + OFF_COL1);
    int* flags  = (int*)(ws + OFF_FLAGS);
    unsigned short* bptr = (unsigned short*)(ws + OFF_PTR);

    hipMemsetAsync(flags, 0, FW_BLOCKS * 16 * sizeof(int), stream);
    k_logtrans<<<4096, 256, 0, stream>>>(tr, lat);
    k_emis<<<dim3(4, TT), 256, 0, stream>>>(ev, epar, prior, E, col0);
    k_forward<<<FW_BLOCKS, FW_THREADS, 0, stream>>>(lat, E, col0, col1, bptr, flags);
    // final column parity: t = 4095 is odd -> written to col1
    k_backtrace<<<1, 64, 0, stream>>>(col1, bptr, seq);
}

// Round 2
// 10931.215 us; speedup vs baseline: 1.6028x; 1.6028x over previous
//
#include <hip/hip_runtime.h>
#include <math.h>

#define NSTATES 1024
#define TT      4096
#define DD      20

#define FW_BLOCKS  64
#define FW_THREADS 256
#define JPB  16      // j per block   (FW_BLOCKS * JPB = NSTATES)
#define NSEG 16      // k segments    (JPB * NSEG = FW_THREADS)
#define KSEG 64      // k per segment (NSEG * KSEG = NSTATES)

#define SENT 0x7FC00000u   // canonical NaN: computed column values are never NaN

// workspace layout (bytes)
#define OFF_LAT   ((size_t)0)               // 4 MB  logA transposed: lat[j*N+k] = log(trans[k][j])
#define OFF_E     ((size_t)4 << 20)         // 16 MB emissions E[t*N+n]
#define OFF_COLS  ((size_t)20 << 20)        // 16 MB per-step columns cols[t*N+j]
#define OFF_PTR   ((size_t)36 << 20)        // 8 MB  u16 backpointers, rows 1..T-1

__global__ void k_init(uint4* __restrict__ cols4) {
    // fill 16 MB of cols with the sentinel (4M words = 1M uint4)
    int id = blockIdx.x * 256 + threadIdx.x;
    cols4[id] = make_uint4(SENT, SENT, SENT, SENT);
}

__global__ void k_logtrans(const float* __restrict__ tr, float* __restrict__ lat) {
    int id = blockIdx.x * 256 + threadIdx.x;        // 1M threads
    int k = id >> 10, j = id & 1023;
    lat[(size_t)j * NSTATES + k] = logf(tr[id]);    // coalesced read, strided write (one-time)
}

__global__ void k_emis(const float* __restrict__ ev, const float* __restrict__ epar,
                       const float* __restrict__ prior, float* __restrict__ E,
                       float* __restrict__ cols) {
    int n = blockIdx.x * 256 + threadIdx.x;         // 4 x 256 = 1024
    int t = blockIdx.y;                             // 0..4095
    const float* ep = epar + (size_t)n * (2 * DD);
    const float* x  = ev + (size_t)t * DD;
    float acc = 0.0f;
    #pragma unroll
    for (int d = 0; d < DD; ++d) {
        float m = ep[2 * d];
        float s = ep[2 * d + 1];
        // faithful to reference: p = (2*pi*s)^(-0.5) * exp(-(x-m)^2/(2*s^2)); logp = log(p)
        float tp   = 6.2831853071795864769f * s;
        float coef = 1.0f / sqrtf(tp);
        float df   = x[d] - m;
        float num  = df * df;
        float den  = 2.0f * (s * s);
        float p    = coef * expf(-num / den);
        acc += logf(p);                             // -inf propagates; values are never NaN
    }
    E[(size_t)t * NSTATES + n] = acc;
    if (t == 0) cols[n] = logf(prior[n]) + acc;     // col0 = log(prior) + logp0 (overwrites sentinel)
}

__global__ __launch_bounds__(FW_THREADS, 1) void k_forward(
    const float* __restrict__ lat, const float* __restrict__ E,
    float* __restrict__ cols, unsigned short* __restrict__ bptr)
{
    __shared__ float prevs[NSTATES];
    __shared__ float smax[NSEG][JPB];
    __shared__ unsigned short sidx[NSEG][JPB];
    const int tid  = threadIdx.x;
    const int jj   = tid & (JPB - 1);
    const int seg  = tid >> 4;                       // 0..15
    const int j    = blockIdx.x * JPB + jj;
    const int kbase = seg * KSEG;
    const float* lrow = lat + (size_t)j * NSTATES + kbase;
    const float lat00 = lat[0];                      // log trans[0][0], for the j==0 quirk

    for (int t = 1; t < TT; ++t) {
        // ---- poll previous column: data-as-flag, relaxed sc1 loads (no L2 invalidate) ----
        const unsigned* p = (const unsigned*)(cols + (size_t)(t - 1) * NSTATES) + tid * 4;
        unsigned w0, w1, w2, w3;
        for (;;) {
            w0 = __hip_atomic_load(p + 0, __ATOMIC_RELAXED, __HIP_MEMORY_SCOPE_AGENT);
            w1 = __hip_atomic_load(p + 1, __ATOMIC_RELAXED, __HIP_MEMORY_SCOPE_AGENT);
            w2 = __hip_atomic_load(p + 2, __ATOMIC_RELAXED, __HIP_MEMORY_SCOPE_AGENT);
            w3 = __hip_atomic_load(p + 3, __ATOMIC_RELAXED, __HIP_MEMORY_SCOPE_AGENT);
            if (w0 != SENT && w1 != SENT && w2 != SENT && w3 != SENT) break;
            __builtin_amdgcn_s_sleep(1);
        }
        prevs[tid * 4 + 0] = __uint_as_float(w0);
        prevs[tid * 4 + 1] = __uint_as_float(w1);
        prevs[tid * 4 + 2] = __uint_as_float(w2);
        prevs[tid * 4 + 3] = __uint_as_float(w3);
        __syncthreads();

        // ---- per-lane scan of its k-segment for its j: first-max (strict >, ascending k) ----
        float best = -__builtin_inff();
        int bidx = kbase;
        #pragma unroll
        for (int u = 0; u < KSEG / 4; ++u) {
            float4 w = *(const float4*)(lrow + u * 4);
            float4 q = *(const float4*)(prevs + kbase + u * 4);
            int k0 = kbase + u * 4;
            float v0 = q.x + w.x;
            float v1 = q.y + w.y;
            float v2 = q.z + w.z;
            float v3 = q.w + w.w;
            if (v0 > best) { best = v0; bidx = k0;     }
            if (v1 > best) { best = v1; bidx = k0 + 1; }
            if (v2 > best) { best = v2; bidx = k0 + 2; }
            if (v3 > best) { best = v3; bidx = k0 + 3; }
        }
        smax[seg][jj] = best;
        sidx[seg][jj] = (unsigned short)bidx;
        __syncthreads();

        // ---- combine 16 segment partials per j (ascending seg => global first-max), publish ----
        if (tid < JPB) {
            float m = smax[0][tid];
            int  mi = sidx[0][tid];
            #pragma unroll
            for (int s2 = 1; s2 < NSEG; ++s2) {
                float v = smax[s2][tid];
                if (v > m) { m = v; mi = sidx[s2][tid]; }
            }
            int jw = blockIdx.x * JPB + tid;
            // reference quirk: j==0 value is forced from state 0 (ptr still stores the true argmax)
            float val = (jw == 0) ? (prevs[0] + lat00) : m;
            float out = val + E[(size_t)t * NSTATES + jw];
            __hip_atomic_store((unsigned*)(cols + (size_t)t * NSTATES) + jw,
                               __float_as_uint(out), __ATOMIC_RELAXED,
                               __HIP_MEMORY_SCOPE_AGENT);
            bptr[(size_t)t * NSTATES + jw] = (unsigned short)mi;
        }
        __syncthreads();   // protect prevs/smax reuse next iteration
    }
}

#define BTC 24  // ptr rows per LDS chunk (48 KB)
__global__ void k_backtrace(const float* __restrict__ lastcol,
                            const unsigned short* __restrict__ bptr,
                            int* __restrict__ seq)
{
    __shared__ unsigned short ring[BTC][NSTATES];
    __shared__ int s_front;
    const int lane = threadIdx.x;   // 64 threads = 1 wave

    // last = first-max argmax over final column
    float best = -__builtin_inff();
    int bi = 0;
    for (int n2 = lane; n2 < NSTATES; n2 += 64) {
        float v = lastcol[n2];
        if (v > best) { best = v; bi = n2; }
    }
    #pragma unroll
    for (int off = 32; off > 0; off >>= 1) {
        float ov = __shfl_xor(best, off);
        int   oi = __shfl_xor(bi, off);
        if (ov > best || (ov == best && oi < bi)) { best = ov; bi = oi; }
    }
    if (lane == 0) { seq[TT] = bi; seq[TT - 1] = bi; s_front = bi; }
    __syncthreads();

    // chase rows r = T-1 .. 1 (seq[r-1] = ptr[r][front]) in descending LDS chunks
    for (int rhi = TT - 1; rhi >= 1; rhi -= BTC) {
        int rlo = rhi - (BTC - 1);
        if (rlo < 1) rlo = 1;
        for (int rr = rlo; rr <= rhi; ++rr) {
            const uint4* src = (const uint4*)(bptr + (size_t)rr * NSTATES);
            uint4* dst = (uint4*)(&ring[rr - rlo][0]);
            dst[lane]      = src[lane];
            dst[lane + 64] = src[lane + 64];
        }
        __syncthreads();
        if (lane == 0) {
            int front = s_front;
            for (int r = rhi; r >= rlo; --r) {
                front = (int)ring[r - rlo][front];
                seq[r - 1] = front;
            }
            s_front = front;
        }
        __syncthreads();
    }
}

extern "C" void kernel_launch(void* const* d_in, const int* in_sizes, int n_in,
                              void* d_out, int out_size, void* d_ws, size_t ws_size,
                              hipStream_t stream) {
    const float* ev    = (const float*)d_in[0];   // [T, D]
    const float* prior = (const float*)d_in[1];   // [N]
    const float* tr    = (const float*)d_in[2];   // [N, N]
    const float* epar  = (const float*)d_in[3];   // [N, D, 2]
    int* seq = (int*)d_out;                       // [T+1]
    char* ws = (char*)d_ws;
    float* lat  = (float*)(ws + OFF_LAT);
    float* E    = (float*)(ws + OFF_E);
    float* cols = (float*)(ws + OFF_COLS);
    unsigned short* bptr = (unsigned short*)(ws + OFF_PTR);

    k_init<<<4096, 256, 0, stream>>>((uint4*)cols);              // sentinel-fill 16 MB
    k_logtrans<<<4096, 256, 0, stream>>>(tr, lat);
    k_emis<<<dim3(4, TT), 256, 0, stream>>>(ev, epar, prior, E, cols);
    k_forward<<<FW_BLOCKS, FW_THREADS, 0, stream>>>(lat, E, cols, bptr);
    k_backtrace<<<1, 64, 0, stream>>>(cols + (size_t)(TT - 1) * NSTATES, bptr, seq);
}